// Round 13
// baseline (55.642 us; speedup 1.0000x reference)
//
#include <hip/hip_runtime.h>
#include <hip/hip_bf16.h>

// Problem constants
#define BB 8
#define CC 64
#define OO 64
#define HH 128
#define WWI 128
#define HWSZ (HH * WWI)     // 16384
#define KK 9                // 3x3 taps
#define II (KK * CC)        // 576

// patch / window geometry (main kernel)
#define PXW 16              // patch width  (x)
#define PYH 16              // patch height (y)
#define WNX 24              // window cols = PXW + 8
#define WNY 24              // window rows = PYH + 8
#define WROWS (WNX * WNY)   // 576 window rows, each 64 ch * 2B = 128B -> 72KB

typedef __attribute__((ext_vector_type(8))) _Float16 half8;
typedef __attribute__((ext_vector_type(2))) _Float16 h2;
typedef __attribute__((ext_vector_type(4))) float f32x4;
typedef __attribute__((ext_vector_type(4))) unsigned int uint4v;

__device__ __forceinline__ int iclamp(int v, int lo, int hi) {
    return v < lo ? lo : (v > hi ? hi : v);
}
__device__ __forceinline__ unsigned short f2h(float f) {
    union { _Float16 h; unsigned short s; } v;
    v.h = (_Float16)f;
    return v.s;
}
__device__ __forceinline__ h2 u2h(unsigned u) {
    union { unsigned u; h2 h; } v;
    v.u = u;
    return v.h;
}

// ---------- prep 1: x [B][C][H][W] f32 -> xt [B][H][W][C] fp16 (LDS transpose)
__global__ __launch_bounds__(256) void prep_xt(const float* __restrict__ x,
                                               unsigned short* __restrict__ xt) {
    __shared__ float tile[64][65];
    const int blk = blockIdx.x;
    const int b = blk & 7;
    const int p0 = (blk >> 3) * 64;
    const int t = threadIdx.x;
    const int a = t >> 6;   // 0..3
    const int q = t & 63;   // 0..63
    const float* xb = x + (size_t)b * CC * HWSZ + p0;
#pragma unroll
    for (int r = 0; r < 16; ++r) {
        int c = r * 4 + a;
        tile[c][q] = xb[(size_t)c * HWSZ + q];   // coalesced read
    }
    __syncthreads();
    unsigned short* xo = xt + ((size_t)b * HWSZ + p0) * CC;
#pragma unroll
    for (int r = 0; r < 16; ++r) {
        int pl = r * 4 + a;
        xo[(size_t)pl * CC + q] = f2h(tile[q][pl]);  // coalesced 2B x 64 write
    }
}

// ---------- prep 2: W -> fragment-ordered fp16 layout
// waf[slab][lane][j], slab = (k*2+kc)*4 + m, value =
//   W.flat[o = m*16+(lane&15)][i = k*64 + kc*32 + (lane>>4)*8 + j]
__global__ void prep_waf(const float* __restrict__ w, unsigned short* __restrict__ waf) {
    int tid = blockIdx.x * 256 + threadIdx.x;
    if (tid < 72 * 512) {
        int slab = tid >> 9;           // 0..71
        int r = tid & 511;
        int l = r >> 3, j = r & 7;
        int m = slab & 3;
        int kc = (slab >> 2) & 1;
        int k = slab >> 3;
        int o = m * 16 + (l & 15);
        int i = k * 64 + kc * 32 + (l >> 4) * 8 + j;
        waf[tid] = f2h(w[(size_t)o * II + i]);
    }
}

// ---------- main: 16x16 patch per block, window in LDS, 8 waves.
// 3-stage software pipeline: COORD(i+2) | READ(i+1) | PROC(i).
// FIX vs r12: cwr ring is 3-deep (distance-2 consumer) — r12's 2-deep ring
// let COORD(i+2) clobber the weights PROC(i) was about to use.
__global__ __launch_bounds__(512, 2) void deform_mfma11(
        const unsigned short* __restrict__ xt,   // [B][H][W][C] fp16
        const float* __restrict__ off,           // [B][2K][H][W]
        const unsigned short* __restrict__ waf,  // frag-ordered W, fp16
        const float* __restrict__ bias,          // [O]
        float* __restrict__ out) {               // [B][O][H][W]
    extern __shared__ unsigned short win[];      // WROWS * 64 shorts = 72KB

    const int blk = blockIdx.x;
    const int b = blk & 7;                 // XCD-ownership: image b on XCD b
    const int pidx = blk >> 3;             // 0..63
    const int y0 = (pidx >> 3) * PYH;      // 8 y-patches
    const int x0 = (pidx & 7) * PXW;       // 8 x-patches
    const int xleft = x0 - 4, ytop = y0 - 4;

    const int t = threadIdx.x;
    const int wave = t >> 6;               // 0..7
    const int lane = t & 63;
    const int fm = lane & 15;              // px-in-tile (B col)
    const int hi = lane >> 4;              // 0..3 (k-chunk)
    const int c0s = hi * 8;                // short offset, kc=0 chunk
    const int c1s = 32 + hi * 8;           // short offset, kc=1 chunk

    const unsigned short* xtb = xt + (size_t)b * HWSZ * CC;
    const float* offpx = off + (size_t)b * 2 * KK * HWSZ
                             + (size_t)(y0 + wave * 2) * WWI + x0 + fm;
    const float fxb = (float)(x0 + fm);
    const float fyb0 = (float)(y0 + wave * 2);
    const float fyb1 = fyb0 + 1.0f;

    // 3-slot offset ring (slot = tap%3); preload taps 0,1 before staging
    float ox[3][2], oy[3][2];
#pragma unroll
    for (int k = 0; k < 2; ++k) {
#pragma unroll
        for (int nt = 0; nt < 2; ++nt) {
            ox[k][nt] = offpx[(size_t)(2 * k + 0) * HWSZ + nt * WWI];
            oy[k][nt] = offpx[(size_t)(2 * k + 1) * HWSZ + nt * WWI];
        }
    }

    // ---- stage window: rows (cy,cx) in [ytop,ytop+23] x [xleft,xleft+23] ----
    {
        const int tch = t & 7;             // 16B chunk within a row
        const int rb = t >> 3;             // 0..63
#pragma unroll
        for (int sw = 0; sw < 9; ++sw) {
            const int r = sw * 64 + rb;    // window row 0..575
            const int wy = r / WNX, wx = r - wy * WNX;
            const int cy = ytop + wy, cx = xleft + wx;
            if (((unsigned)cy < (unsigned)HH) && ((unsigned)cx < (unsigned)WWI)) {
                const uint4v v = *(const uint4v*)(xtb + (size_t)(cy * WWI + cx) * CC + tch * 8);
                *(uint4v*)&win[r * CC + ((tch ^ (r & 7)) << 3)] = v;  // swizzled
            }
        }
    }
    __syncthreads();

    f32x4 acc[2][4];
#pragma unroll
    for (int nt = 0; nt < 2; ++nt)
#pragma unroll
        for (int m = 0; m < 4; ++m) acc[nt][m] = (f32x4)(0.0f);

    // pipeline state (all compile-time indexed)
    float  cwr[3][4];      // folded bilinear weights, ring by u%3 (distance-2!)
    int    lr[2][4];       // window rows (r00,r01,r10,r11), ring by u&1
    int    gidr[2][4];     // global fallback rows
    bool   inwr[2];
    uint4v cb[2][8];       // corner vectors
    half8  af[2][8];       // A-fragments, ring by tap&1

#define LDW(r, kc) (*(const uint4v*)&win[(r) * CC + ((((hi) + ((kc) << 2)) ^ ((r) & 7)) << 3)])

    // COORD(u): weights/rows for unit u; even u: prefetch offsets tap+2, A-frags tap u/2
#define COORD(u) do {                                                           \
        const int s_ = (u) & 1;                                                 \
        const int w_ = (u) % 3;                                                 \
        const int k_ = (u) >> 1;                                                \
        if (((u) & 1) == 0) {                                                   \
            if (k_ + 2 < KK) {                                                  \
                ox[(k_ + 2) % 3][0] = offpx[(size_t)(2 * (k_ + 2) + 0) * HWSZ];         \
                ox[(k_ + 2) % 3][1] = offpx[(size_t)(2 * (k_ + 2) + 0) * HWSZ + WWI];   \
                oy[(k_ + 2) % 3][0] = offpx[(size_t)(2 * (k_ + 2) + 1) * HWSZ];         \
                oy[(k_ + 2) % 3][1] = offpx[(size_t)(2 * (k_ + 2) + 1) * HWSZ + WWI];   \
            }                                                                   \
            const unsigned short* wk_ = waf + (size_t)k_ * 8 * 512 + lane * 8;  \
            _Pragma("unroll")                                                   \
            for (int q = 0; q < 8; ++q)                                         \
                af[k_ & 1][q] = *(const half8*)(wk_ + (size_t)q * 512);         \
        }                                                                       \
        const float gx = ox[k_ % 3][s_] + fxb;                                  \
        const float gy = oy[k_ % 3][s_] + (s_ ? fyb1 : fyb0);                   \
        const float fxf = floorf(gx), fyf = floorf(gy);                         \
        const float fx = gx - fxf, fy = gy - fyf;                               \
        const int ux0 = (int)fxf - 1, ux1 = (int)fxf;                           \
        const int uy0 = (int)fyf - 1, uy1 = (int)fyf;                           \
        const float vx0 = ((unsigned)ux0 < (unsigned)WWI) ? 1.0f : 0.0f;        \
        const float vx1 = ((unsigned)ux1 < (unsigned)WWI) ? 1.0f : 0.0f;        \
        const float vy0 = ((unsigned)uy0 < (unsigned)HH) ? 1.0f : 0.0f;         \
        const float vy1 = ((unsigned)uy1 < (unsigned)HH) ? 1.0f : 0.0f;         \
        cwr[w_][0] = (1.0f - fy) * (1.0f - fx) * vy0 * vx0;                     \
        cwr[w_][1] = (1.0f - fy) * fx          * vy0 * vx1;                     \
        cwr[w_][2] = fy          * (1.0f - fx) * vy1 * vx0;                     \
        cwr[w_][3] = fy          * fx          * vy1 * vx1;                     \
        const int cx0 = iclamp(ux0, 0, WWI - 1), cx1 = iclamp(ux1, 0, WWI - 1); \
        const int cy0 = iclamp(uy0, 0, HH - 1),  cy1 = iclamp(uy1, 0, HH - 1);  \
        inwr[s_] = (cx0 >= xleft) & (cx1 <= xleft + WNX - 1)                    \
                 & (cy0 >= ytop) & (cy1 <= ytop + WNY - 1);                     \
        gidr[s_][0] = cy0 * WWI + cx0;  gidr[s_][1] = cy0 * WWI + cx1;          \
        gidr[s_][2] = cy1 * WWI + cx0;  gidr[s_][3] = cy1 * WWI + cx1;          \
        const int wx0 = iclamp(cx0 - xleft, 0, WNX - 1);                        \
        const int wx1 = iclamp(cx1 - xleft, 0, WNX - 1);                        \
        const int wy0 = iclamp(cy0 - ytop, 0, WNY - 1);                         \
        const int wy1 = iclamp(cy1 - ytop, 0, WNY - 1);                         \
        lr[s_][0] = wy0 * WNX + wx0;  lr[s_][1] = wy0 * WNX + wx1;              \
        lr[s_][2] = wy1 * WNX + wx0;  lr[s_][3] = wy1 * WNX + wx1;              \
    } while (0)

    // READ(u): 8 ds_read_b128; rare exec-masked global overwrite
#define READ(u) do {                                                            \
        const int s_ = (u) & 1;                                                 \
        cb[s_][0] = LDW(lr[s_][0], 0);  cb[s_][1] = LDW(lr[s_][0], 1);          \
        cb[s_][2] = LDW(lr[s_][1], 0);  cb[s_][3] = LDW(lr[s_][1], 1);          \
        cb[s_][4] = LDW(lr[s_][2], 0);  cb[s_][5] = LDW(lr[s_][2], 1);          \
        cb[s_][6] = LDW(lr[s_][3], 0);  cb[s_][7] = LDW(lr[s_][3], 1);          \
        if (!inwr[s_]) {                                                        \
            const unsigned short* g00 = xtb + (size_t)gidr[s_][0] * CC;         \
            const unsigned short* g01 = xtb + (size_t)gidr[s_][1] * CC;         \
            const unsigned short* g10 = xtb + (size_t)gidr[s_][2] * CC;         \
            const unsigned short* g11 = xtb + (size_t)gidr[s_][3] * CC;         \
            cb[s_][0] = *(const uint4v*)(g00 + c0s);                            \
            cb[s_][1] = *(const uint4v*)(g00 + c1s);                            \
            cb[s_][2] = *(const uint4v*)(g01 + c0s);                            \
            cb[s_][3] = *(const uint4v*)(g01 + c1s);                            \
            cb[s_][4] = *(const uint4v*)(g10 + c0s);                            \
            cb[s_][5] = *(const uint4v*)(g10 + c1s);                            \
            cb[s_][6] = *(const uint4v*)(g11 + c0s);                            \
            cb[s_][7] = *(const uint4v*)(g11 + c1s);                            \
        }                                                                       \
    } while (0)

    // PROC(u): pin corners (loads complete HERE), interp, 8 MFMA
#define PROC(u) do {                                                            \
        const int s_ = (u) & 1;                                                 \
        const int w_ = (u) % 3;                                                 \
        const int ka_ = ((u) >> 1) & 1;                                         \
        asm volatile("" : "+v"(cb[s_][0]), "+v"(cb[s_][1]),                     \
                          "+v"(cb[s_][2]), "+v"(cb[s_][3]),                     \
                          "+v"(cb[s_][4]), "+v"(cb[s_][5]),                     \
                          "+v"(cb[s_][6]), "+v"(cb[s_][7]));                    \
        const _Float16 hw00 = (_Float16)cwr[w_][0];                             \
        const _Float16 hw01 = (_Float16)cwr[w_][1];                             \
        const _Float16 hw10 = (_Float16)cwr[w_][2];                             \
        const _Float16 hw11 = (_Float16)cwr[w_][3];                             \
        const h2 w00v = {hw00, hw00}, w01v = {hw01, hw01};                      \
        const h2 w10v = {hw10, hw10}, w11v = {hw11, hw11};                      \
        half8 bf0, bf1;                                                         \
        h2* rp0 = (h2*)&bf0;                                                    \
        h2* rp1 = (h2*)&bf1;                                                    \
        _Pragma("unroll")                                                       \
        for (int i = 0; i < 4; ++i) {                                           \
            h2 r0 = u2h(cb[s_][0][i]) * w00v;                                   \
            r0 += u2h(cb[s_][2][i]) * w01v;                                     \
            r0 += u2h(cb[s_][4][i]) * w10v;                                     \
            r0 += u2h(cb[s_][6][i]) * w11v;                                     \
            rp0[i] = r0;                                                        \
            h2 r1 = u2h(cb[s_][1][i]) * w00v;                                   \
            r1 += u2h(cb[s_][3][i]) * w01v;                                     \
            r1 += u2h(cb[s_][5][i]) * w10v;                                     \
            r1 += u2h(cb[s_][7][i]) * w11v;                                     \
            rp1[i] = r1;                                                        \
        }                                                                       \
        _Pragma("unroll")                                                       \
        for (int m = 0; m < 4; ++m)                                             \
            acc[s_][m] = __builtin_amdgcn_mfma_f32_16x16x32_f16(                \
                af[ka_][m], bf0, acc[s_][m], 0, 0, 0);                          \
        _Pragma("unroll")                                                       \
        for (int m = 0; m < 4; ++m)                                             \
            acc[s_][m] = __builtin_amdgcn_mfma_f32_16x16x32_f16(                \
                af[ka_][4 + m], bf1, acc[s_][m], 0, 0, 0);                      \
    } while (0)

    // ---- 3-stage pipeline over 18 (tap,nt) units ----
    COORD(0);  COORD(1);  READ(0);
    COORD(2);  READ(1);   PROC(0);
    COORD(3);  READ(2);   PROC(1);
    COORD(4);  READ(3);   PROC(2);
    COORD(5);  READ(4);   PROC(3);
    COORD(6);  READ(5);   PROC(4);
    COORD(7);  READ(6);   PROC(5);
    COORD(8);  READ(7);   PROC(6);
    COORD(9);  READ(8);   PROC(7);
    COORD(10); READ(9);   PROC(8);
    COORD(11); READ(10);  PROC(9);
    COORD(12); READ(11);  PROC(10);
    COORD(13); READ(12);  PROC(11);
    COORD(14); READ(13);  PROC(12);
    COORD(15); READ(14);  PROC(13);
    COORD(16); READ(15);  PROC(14);
    COORD(17); READ(16);  PROC(15);
    READ(17);  PROC(16);
    PROC(17);

#undef COORD
#undef READ
#undef PROC
#undef LDW

    // epilogue: D col = fm (px), D row = hi*4 + j within m-tile -> o = m*16+hi*4+j
#pragma unroll
    for (int nt = 0; nt < 2; ++nt) {
        float* outb = out + (size_t)b * OO * HWSZ
                          + (size_t)(y0 + wave * 2 + nt) * WWI + x0 + fm;
#pragma unroll
        for (int m = 0; m < 4; ++m) {
            const int ob = m * 16 + hi * 4;
            const float4 bs = *(const float4*)(bias + ob);
#pragma unroll
            for (int j = 0; j < 4; ++j) {
                outb[(size_t)(ob + j) * HWSZ] = acc[nt][m][j] + ((const float*)&bs)[j];
            }
        }
    }
}

// ---------- fallback (round-1 fp32 path, used only if ws too small) ----------
__global__ __launch_bounds__(256) void deform_conv_fallback(
        const float* __restrict__ x, const float* __restrict__ off,
        const float* __restrict__ wmat, const float* __restrict__ bias,
        float* __restrict__ out) {
    const int b = blockIdx.y;
    const int p = blockIdx.x * 256 + threadIdx.x;
    const int wo = p & (WWI - 1);
    const int ho = p >> 7;
    const float* xb = x + (size_t)b * CC * HWSZ;
    const float* offb = off + (size_t)b * 2 * KK * HWSZ + p;
    float acc[OO];
#pragma unroll
    for (int o = 0; o < OO; ++o) acc[o] = 0.0f;
#pragma unroll 1
    for (int k = 0; k < KK; ++k) {
        const float gx = offb[(size_t)(2 * k + 0) * HWSZ] + (float)wo;
        const float gy = offb[(size_t)(2 * k + 1) * HWSZ] + (float)ho;
        const float fxf = floorf(gx), fyf = floorf(gy);
        const float fx = gx - fxf, fy = gy - fyf;
        const int ux0 = (int)fxf - 1, ux1 = (int)fxf;
        const int uy0 = (int)fyf - 1, uy1 = (int)fyf;
        const float vx0 = ((unsigned)ux0 < (unsigned)WWI) ? 1.0f : 0.0f;
        const float vx1 = ((unsigned)ux1 < (unsigned)WWI) ? 1.0f : 0.0f;
        const float vy0 = ((unsigned)uy0 < (unsigned)HH) ? 1.0f : 0.0f;
        const float vy1 = ((unsigned)uy1 < (unsigned)HH) ? 1.0f : 0.0f;
        const float w00 = (1.0f - fy) * (1.0f - fx) * vy0 * vx0;
        const float w01 = (1.0f - fy) * fx * vy0 * vx1;
        const float w10 = fy * (1.0f - fx) * vy1 * vx0;
        const float w11 = fy * fx * vy1 * vx1;
        const int cx0 = iclamp(ux0, 0, WWI - 1), cx1 = iclamp(ux1, 0, WWI - 1);
        const int cy0 = iclamp(uy0, 0, HH - 1), cy1 = iclamp(uy1, 0, HH - 1);
        const int i00 = cy0 * WWI + cx0, i01 = cy0 * WWI + cx1;
        const int i10 = cy1 * WWI + cx0, i11 = cy1 * WWI + cx1;
#pragma unroll 4
        for (int c = 0; c < CC; ++c) {
            const float* xc = xb + (size_t)c * HWSZ;
            const float v = w00 * xc[i00] + w01 * xc[i01] + w10 * xc[i10] + w11 * xc[i11];
            const float* wrow = wmat + (size_t)(k * CC + c);
#pragma unroll
            for (int o = 0; o < OO; ++o) acc[o] = fmaf(wrow[(size_t)o * II], v, acc[o]);
        }
    }
    float* outb = out + (size_t)b * OO * HWSZ + p;
#pragma unroll
    for (int o = 0; o < OO; ++o) outb[(size_t)o * HWSZ] = acc[o] + bias[o];
}

extern "C" void kernel_launch(void* const* d_in, const int* in_sizes, int n_in,
                              void* d_out, int out_size, void* d_ws, size_t ws_size,
                              hipStream_t stream) {
    const float* x    = (const float*)d_in[0];
    const float* off  = (const float*)d_in[1];
    const float* w    = (const float*)d_in[2];
    const float* bias = (const float*)d_in[3];
    float* out = (float*)d_out;

    const size_t xt_bytes  = (size_t)BB * HWSZ * CC * sizeof(unsigned short); // 16.78 MB
    const size_t waf_bytes = (size_t)72 * 512 * sizeof(unsigned short);       // 73728 B

    if (ws_size >= xt_bytes + waf_bytes) {
        unsigned short* xt  = (unsigned short*)d_ws;
        unsigned short* wfp = (unsigned short*)((char*)d_ws + xt_bytes);
        prep_xt<<<dim3((HWSZ / 64) * BB), 256, 0, stream>>>(x, xt);
        prep_waf<<<(72 * 512 + 255) / 256, 256, 0, stream>>>(w, wfp);
        // 8 images x (8 y-patches * 8 x-patches) = 512 blocks, 72KB dyn LDS
        deform_mfma11<<<dim3(BB * (HH / PYH) * (WWI / PXW)), dim3(512),
                        WROWS * CC * sizeof(unsigned short), stream>>>(
            xt, off, wfp, bias, out);
    } else {
        deform_conv_fallback<<<dim3(HWSZ / 256, BB), 256, 0, stream>>>(x, off, w, bias, out);
    }
}

// Round 14
// 50.400 us; speedup vs baseline: 1.1040x; 1.1040x over previous
//
#include <hip/hip_runtime.h>

// Problem constants
#define BB 8
#define CC 64
#define OO 64
#define HH 128
#define WWI 128
#define HWSZ (HH * WWI)     // 16384
#define KK 9                // 3x3 taps
#define II (KK * CC)        // 576

// patch / window geometry (main kernel)
#define PXW 16              // patch width  (x)
#define PYH 16              // patch height (y)
#define WNX 24              // window cols = PXW + 8
#define WNY 24              // window rows = PYH + 8
#define WROWS (WNX * WNY)   // 576 window rows, each 64 ch * 2B = 128B -> 72KB

typedef __attribute__((ext_vector_type(8))) _Float16 half8;
typedef __attribute__((ext_vector_type(2))) _Float16 h2;
typedef __attribute__((ext_vector_type(4))) float f32x4;
typedef __attribute__((ext_vector_type(4))) unsigned int uint4v;

__device__ __forceinline__ int iclamp(int v, int lo, int hi) {
    return v < lo ? lo : (v > hi ? hi : v);
}
__device__ __forceinline__ unsigned short f2h(float f) {
    union { _Float16 h; unsigned short s; } v;
    v.h = (_Float16)f;
    return v.s;
}
__device__ __forceinline__ h2 u2h(unsigned u) {
    union { unsigned u; h2 h; } v;
    v.u = u;
    return v.h;
}

// ---------- prep: W -> fragment-ordered fp16 layout
// waf[slab][lane][j], slab = (k*2+kc)*4 + m, value =
//   W.flat[o = m*16+(lane&15)][i = k*64 + kc*32 + (lane>>4)*8 + j]
__global__ void prep_waf(const float* __restrict__ w, unsigned short* __restrict__ waf) {
    int tid = blockIdx.x * 256 + threadIdx.x;
    if (tid < 72 * 512) {
        int slab = tid >> 9;           // 0..71
        int r = tid & 511;
        int l = r >> 3, j = r & 7;
        int m = slab & 3;
        int kc = (slab >> 2) & 1;
        int k = slab >> 3;
        int o = m * 16 + (l & 15);
        int i = k * 64 + kc * 32 + (l >> 4) * 8 + j;
        waf[tid] = f2h(w[(size_t)o * II + i]);
    }
}

// ---------- main: 16x16 patch per block, window staged DIRECTLY from x
// (f32 NCHW -> fp16 LDS, conversion absorbed into the idle VMEM phase).
// Depth-2 (tap,nt)-unit register pipeline identical to the validated r11.
__global__ __launch_bounds__(512, 2) void deform_mfma12(
        const float* __restrict__ x,             // [B][C][H][W] f32
        const float* __restrict__ off,           // [B][2K][H][W]
        const unsigned short* __restrict__ waf,  // frag-ordered W, fp16
        const float* __restrict__ bias,          // [O]
        float* __restrict__ out) {               // [B][O][H][W]
    extern __shared__ unsigned short win[];      // WROWS * 64 shorts = 72KB

    const int blk = blockIdx.x;
    const int b = blk & 7;                 // XCD-ownership: image b on XCD b
    const int pidx = blk >> 3;             // 0..63
    const int y0 = (pidx >> 3) * PYH;      // 8 y-patches
    const int x0 = (pidx & 7) * PXW;       // 8 x-patches
    const int xleft = x0 - 4, ytop = y0 - 4;

    const int t = threadIdx.x;
    const int wave = t >> 6;               // 0..7
    const int lane = t & 63;
    const int fm = lane & 15;              // px-in-tile (B col)
    const int hi = lane >> 4;              // 0..3 (k-chunk)
    const int c0s = hi * 8;                // channel base, kc=0 chunk
    const int c1s = 32 + hi * 8;           // channel base, kc=1 chunk

    const float* xb = x + (size_t)b * CC * HWSZ;
    const float* offpx = off + (size_t)b * 2 * KK * HWSZ
                             + (size_t)(y0 + wave * 2) * WWI + x0 + fm;

    // 3-slot offset ring (slot = tap%3); preload taps 0,1 before staging
    float ox[3][2], oy[3][2];
#pragma unroll
    for (int k = 0; k < 2; ++k) {
#pragma unroll
        for (int nt = 0; nt < 2; ++nt) {
            ox[k][nt] = offpx[(size_t)(2 * k + 0) * HWSZ + nt * WWI];
            oy[k][nt] = offpx[(size_t)(2 * k + 1) * HWSZ + nt * WWI];
        }
    }

    // ---- stage window DIRECTLY from x: task (c=lane, wy=wave+8i) reads the
    // 24-float image row segment, converts to fp16, writes one full 128B LDS
    // row per (g,e) wave-instruction (banks = c>>1, 2 lanes/bank = free).
    {
#pragma unroll
        for (int i = 0; i < 3; ++i) {
            const int task = t + i * 512;
            const int c  = task & 63;          // == lane
            const int wy = task >> 6;          // == wave + 8*i, 0..23
            const int cy = ytop + wy;
            if ((unsigned)cy < (unsigned)HH) {
                const float* src = xb + (size_t)c * HWSZ + (size_t)cy * WWI;
                const int chunk = c >> 3;
                const int cin = c & 7;
#pragma unroll
                for (int g = 0; g < 6; ++g) {
                    const int cx = xleft + g * 4;            // ≡ 0 mod 4
                    if ((unsigned)cx < (unsigned)(WWI - 3)) {  // group fully in
                        const float4 v = *(const float4*)(src + cx);
                        const int rbase = wy * WNX + (cx - xleft);
#pragma unroll
                        for (int e = 0; e < 4; ++e) {
                            const int r = rbase + e;
                            win[r * CC + ((chunk ^ (r & 7)) << 3) + cin] =
                                f2h(((const float*)&v)[e]);
                        }
                    }
                }
            }
        }
    }
    __syncthreads();

    f32x4 acc[2][4];
#pragma unroll
    for (int nt = 0; nt < 2; ++nt)
#pragma unroll
        for (int m = 0; m < 4; ++m) acc[nt][m] = (f32x4)(0.0f);

    // pipeline state (all indices compile-time constants after macro expansion)
    uint4v cb[2][8];       // corner vectors, buffer = unit&1 (== nt)
    float  cw[2][4];       // folded bilinear weights
    bool   inwf[2];        // in-window flag
    int    gidx[2][4];     // global fallback pixel indices
    half8  afb[2][8];      // A-fragments, buffer = tap&1

#define LDSRD(r, kc) (*(const uint4v*)&win[(r) * CC + ((((hi) + ((kc) << 2)) ^ ((r) & 7)) << 3)])

    // ISSUE(u): coords + 8 LDS corner reads for unit u; on nt==0 also prefetch
    // offsets for tap k+2 (ring) and A-frags for tap k.
#define ISSUE(u) do {                                                           \
        if ((((u) & 1) == 0) && (((u) >> 1) + 2 < KK)) {                        \
            _Pragma("unroll")                                                   \
            for (int nt = 0; nt < 2; ++nt) {                                    \
                ox[(((u) >> 1) + 2) % 3][nt] =                                  \
                    offpx[(size_t)(2 * (((u) >> 1) + 2) + 0) * HWSZ + nt * WWI];\
                oy[(((u) >> 1) + 2) % 3][nt] =                                  \
                    offpx[(size_t)(2 * (((u) >> 1) + 2) + 1) * HWSZ + nt * WWI];\
            }                                                                   \
        }                                                                       \
        if (((u) & 1) == 0) {                                                   \
            const unsigned short* wk = waf + (size_t)((u) >> 1) * 8 * 512 + lane * 8; \
            _Pragma("unroll")                                                   \
            for (int q = 0; q < 8; ++q)                                         \
                afb[((u) >> 1) & 1][q] = *(const half8*)(wk + (size_t)q * 512); \
        }                                                                       \
        const float gx = ox[((u) >> 1) % 3][(u) & 1] + (float)(x0 + fm);        \
        const float gy = oy[((u) >> 1) % 3][(u) & 1] + (float)(y0 + wave * 2 + ((u) & 1)); \
        const float fxf = floorf(gx), fyf = floorf(gy);                         \
        const float fx = gx - fxf, fy = gy - fyf;                               \
        const int ux0 = (int)fxf - 1, ux1 = (int)fxf;                           \
        const int uy0 = (int)fyf - 1, uy1 = (int)fyf;                           \
        const float vx0 = ((unsigned)ux0 < (unsigned)WWI) ? 1.0f : 0.0f;        \
        const float vx1 = ((unsigned)ux1 < (unsigned)WWI) ? 1.0f : 0.0f;        \
        const float vy0 = ((unsigned)uy0 < (unsigned)HH) ? 1.0f : 0.0f;         \
        const float vy1 = ((unsigned)uy1 < (unsigned)HH) ? 1.0f : 0.0f;         \
        cw[(u) & 1][0] = (1.0f - fy) * (1.0f - fx) * vy0 * vx0;                 \
        cw[(u) & 1][1] = (1.0f - fy) * fx          * vy0 * vx1;                 \
        cw[(u) & 1][2] = fy          * (1.0f - fx) * vy1 * vx0;                 \
        cw[(u) & 1][3] = fy          * fx          * vy1 * vx1;                 \
        const int cx0 = iclamp(ux0, 0, WWI - 1), cx1 = iclamp(ux1, 0, WWI - 1); \
        const int cy0 = iclamp(uy0, 0, HH - 1),  cy1 = iclamp(uy1, 0, HH - 1);  \
        inwf[(u) & 1] = (cx0 >= xleft) & (cx1 <= xleft + WNX - 1)               \
                      & (cy0 >= ytop) & (cy1 <= ytop + WNY - 1);                \
        gidx[(u) & 1][0] = cy0 * WWI + cx0;  gidx[(u) & 1][1] = cy0 * WWI + cx1;\
        gidx[(u) & 1][2] = cy1 * WWI + cx0;  gidx[(u) & 1][3] = cy1 * WWI + cx1;\
        const int wx0 = iclamp(cx0 - xleft, 0, WNX - 1);                        \
        const int wx1 = iclamp(cx1 - xleft, 0, WNX - 1);                        \
        const int wy0 = iclamp(cy0 - ytop, 0, WNY - 1);                         \
        const int wy1 = iclamp(cy1 - ytop, 0, WNY - 1);                         \
        const int r00 = wy0 * WNX + wx0, r01 = wy0 * WNX + wx1;                 \
        const int r10 = wy1 * WNX + wx0, r11 = wy1 * WNX + wx1;                 \
        cb[(u) & 1][0] = LDSRD(r00, 0);  cb[(u) & 1][1] = LDSRD(r00, 1);        \
        cb[(u) & 1][2] = LDSRD(r01, 0);  cb[(u) & 1][3] = LDSRD(r01, 1);        \
        cb[(u) & 1][4] = LDSRD(r10, 0);  cb[(u) & 1][5] = LDSRD(r10, 1);        \
        cb[(u) & 1][6] = LDSRD(r11, 0);  cb[(u) & 1][7] = LDSRD(r11, 1);        \
    } while (0)

    // f32 fallback gather for one corner chunk (8 channels) from x
#define FBK(dst, gi, cbase) do {                                                \
        const float* xg_ = xb + (size_t)(gi);                                   \
        uint4v tmp_;                                                            \
        _Pragma("unroll")                                                       \
        for (int jj = 0; jj < 4; ++jj) {                                        \
            union { h2 h; unsigned u; } pp_;                                    \
            pp_.h = (h2){(_Float16)xg_[(size_t)((cbase) + 2 * jj) * HWSZ],      \
                         (_Float16)xg_[(size_t)((cbase) + 2 * jj + 1) * HWSZ]}; \
            tmp_[jj] = pp_.u;                                                   \
        }                                                                       \
        (dst) = tmp_;                                                           \
    } while (0)

    // PROC(u): pin corner regs (loads complete HERE), rare f32 fallback,
    // packed-fp16 interp, 8 MFMA into acc[nt].
#define PROC(u) do {                                                            \
        asm volatile("" : "+v"(cb[(u) & 1][0]), "+v"(cb[(u) & 1][1]),           \
                          "+v"(cb[(u) & 1][2]), "+v"(cb[(u) & 1][3]),           \
                          "+v"(cb[(u) & 1][4]), "+v"(cb[(u) & 1][5]),           \
                          "+v"(cb[(u) & 1][6]), "+v"(cb[(u) & 1][7]));          \
        uint4v A0 = cb[(u) & 1][0], A1 = cb[(u) & 1][1];                        \
        uint4v B0 = cb[(u) & 1][2], B1 = cb[(u) & 1][3];                        \
        uint4v C0 = cb[(u) & 1][4], C1 = cb[(u) & 1][5];                        \
        uint4v D0 = cb[(u) & 1][6], D1 = cb[(u) & 1][7];                        \
        if (!inwf[(u) & 1]) {                                                   \
            FBK(A0, gidx[(u) & 1][0], c0s);  FBK(A1, gidx[(u) & 1][0], c1s);    \
            FBK(B0, gidx[(u) & 1][1], c0s);  FBK(B1, gidx[(u) & 1][1], c1s);    \
            FBK(C0, gidx[(u) & 1][2], c0s);  FBK(C1, gidx[(u) & 1][2], c1s);    \
            FBK(D0, gidx[(u) & 1][3], c0s);  FBK(D1, gidx[(u) & 1][3], c1s);    \
        }                                                                       \
        const _Float16 hw00 = (_Float16)cw[(u) & 1][0];                         \
        const _Float16 hw01 = (_Float16)cw[(u) & 1][1];                         \
        const _Float16 hw10 = (_Float16)cw[(u) & 1][2];                         \
        const _Float16 hw11 = (_Float16)cw[(u) & 1][3];                         \
        const h2 w00v = {hw00, hw00}, w01v = {hw01, hw01};                      \
        const h2 w10v = {hw10, hw10}, w11v = {hw11, hw11};                      \
        half8 bf0, bf1;                                                         \
        h2* rp0 = (h2*)&bf0;                                                    \
        h2* rp1 = (h2*)&bf1;                                                    \
        _Pragma("unroll")                                                       \
        for (int i = 0; i < 4; ++i) {                                           \
            h2 r0 = u2h(A0[i]) * w00v;                                          \
            r0 += u2h(B0[i]) * w01v;                                            \
            r0 += u2h(C0[i]) * w10v;                                            \
            r0 += u2h(D0[i]) * w11v;                                            \
            rp0[i] = r0;                                                        \
            h2 r1 = u2h(A1[i]) * w00v;                                          \
            r1 += u2h(B1[i]) * w01v;                                            \
            r1 += u2h(C1[i]) * w10v;                                            \
            r1 += u2h(D1[i]) * w11v;                                            \
            rp1[i] = r1;                                                        \
        }                                                                       \
        _Pragma("unroll")                                                       \
        for (int m = 0; m < 4; ++m)                                             \
            acc[(u) & 1][m] = __builtin_amdgcn_mfma_f32_16x16x32_f16(           \
                afb[((u) >> 1) & 1][m], bf0, acc[(u) & 1][m], 0, 0, 0);         \
        _Pragma("unroll")                                                       \
        for (int m = 0; m < 4; ++m)                                             \
            acc[(u) & 1][m] = __builtin_amdgcn_mfma_f32_16x16x32_f16(           \
                afb[((u) >> 1) & 1][4 + m], bf1, acc[(u) & 1][m], 0, 0, 0);     \
    } while (0)

    // Schedule (r11-validated): I0 I1 P0 I2 P1 ... I17 P16 P17
    ISSUE(0);  ISSUE(1);
    PROC(0);   ISSUE(2);
    PROC(1);   ISSUE(3);
    PROC(2);   ISSUE(4);
    PROC(3);   ISSUE(5);
    PROC(4);   ISSUE(6);
    PROC(5);   ISSUE(7);
    PROC(6);   ISSUE(8);
    PROC(7);   ISSUE(9);
    PROC(8);   ISSUE(10);
    PROC(9);   ISSUE(11);
    PROC(10);  ISSUE(12);
    PROC(11);  ISSUE(13);
    PROC(12);  ISSUE(14);
    PROC(13);  ISSUE(15);
    PROC(14);  ISSUE(16);
    PROC(15);  ISSUE(17);
    PROC(16);
    PROC(17);

#undef ISSUE
#undef PROC
#undef FBK
#undef LDSRD

    // epilogue: D col = fm (px), D row = hi*4 + j within m-tile -> o = m*16+hi*4+j
#pragma unroll
    for (int nt = 0; nt < 2; ++nt) {
        float* outb = out + (size_t)b * OO * HWSZ
                          + (size_t)(y0 + wave * 2 + nt) * WWI + x0 + fm;
#pragma unroll
        for (int m = 0; m < 4; ++m) {
            const int ob = m * 16 + hi * 4;
            const float4 bs = *(const float4*)(bias + ob);
#pragma unroll
            for (int j = 0; j < 4; ++j) {
                outb[(size_t)(ob + j) * HWSZ] = acc[nt][m][j] + ((const float*)&bs)[j];
            }
        }
    }
}

// ---------- fallback (round-1 fp32 path, used only if ws too small) ----------
__global__ __launch_bounds__(256) void deform_conv_fallback(
        const float* __restrict__ x, const float* __restrict__ off,
        const float* __restrict__ wmat, const float* __restrict__ bias,
        float* __restrict__ out) {
    const int b = blockIdx.y;
    const int p = blockIdx.x * 256 + threadIdx.x;
    const int wo = p & (WWI - 1);
    const int ho = p >> 7;
    const float* xb = x + (size_t)b * CC * HWSZ;
    const float* offb = off + (size_t)b * 2 * KK * HWSZ + p;
    float acc[OO];
#pragma unroll
    for (int o = 0; o < OO; ++o) acc[o] = 0.0f;
#pragma unroll 1
    for (int k = 0; k < KK; ++k) {
        const float gx = offb[(size_t)(2 * k + 0) * HWSZ] + (float)wo;
        const float gy = offb[(size_t)(2 * k + 1) * HWSZ] + (float)ho;
        const float fxf = floorf(gx), fyf = floorf(gy);
        const float fx = gx - fxf, fy = gy - fyf;
        const int ux0 = (int)fxf - 1, ux1 = (int)fxf;
        const int uy0 = (int)fyf - 1, uy1 = (int)fyf;
        const float vx0 = ((unsigned)ux0 < (unsigned)WWI) ? 1.0f : 0.0f;
        const float vx1 = ((unsigned)ux1 < (unsigned)WWI) ? 1.0f : 0.0f;
        const float vy0 = ((unsigned)uy0 < (unsigned)HH) ? 1.0f : 0.0f;
        const float vy1 = ((unsigned)uy1 < (unsigned)HH) ? 1.0f : 0.0f;
        const float w00 = (1.0f - fy) * (1.0f - fx) * vy0 * vx0;
        const float w01 = (1.0f - fy) * fx * vy0 * vx1;
        const float w10 = fy * (1.0f - fx) * vy1 * vx0;
        const float w11 = fy * fx * vy1 * vx1;
        const int cx0 = iclamp(ux0, 0, WWI - 1), cx1 = iclamp(ux1, 0, WWI - 1);
        const int cy0 = iclamp(uy0, 0, HH - 1), cy1 = iclamp(uy1, 0, HH - 1);
        const int i00 = cy0 * WWI + cx0, i01 = cy0 * WWI + cx1;
        const int i10 = cy1 * WWI + cx0, i11 = cy1 * WWI + cx1;
#pragma unroll 4
        for (int c = 0; c < CC; ++c) {
            const float* xc = xb + (size_t)c * HWSZ;
            const float v = w00 * xc[i00] + w01 * xc[i01] + w10 * xc[i10] + w11 * xc[i11];
            const float* wrow = wmat + (size_t)(k * CC + c);
#pragma unroll
            for (int o = 0; o < OO; ++o) acc[o] = fmaf(wrow[(size_t)o * II], v, acc[o]);
        }
    }
    float* outb = out + (size_t)b * OO * HWSZ + p;
#pragma unroll
    for (int o = 0; o < OO; ++o) outb[(size_t)o * HWSZ] = acc[o] + bias[o];
}

extern "C" void kernel_launch(void* const* d_in, const int* in_sizes, int n_in,
                              void* d_out, int out_size, void* d_ws, size_t ws_size,
                              hipStream_t stream) {
    const float* x    = (const float*)d_in[0];
    const float* off  = (const float*)d_in[1];
    const float* w    = (const float*)d_in[2];
    const float* bias = (const float*)d_in[3];
    float* out = (float*)d_out;

    const size_t waf_bytes = (size_t)72 * 512 * sizeof(unsigned short);  // 73728 B

    if (ws_size >= waf_bytes) {
        unsigned short* wfp = (unsigned short*)d_ws;
        prep_waf<<<(72 * 512 + 255) / 256, 256, 0, stream>>>(w, wfp);
        // 8 images x (8 y-patches * 8 x-patches) = 512 blocks, 72KB dyn LDS
        deform_mfma12<<<dim3(BB * (HH / PYH) * (WWI / PXW)), dim3(512),
                        WROWS * CC * sizeof(unsigned short), stream>>>(
            x, off, wfp, bias, out);
    } else {
        deform_conv_fallback<<<dim3(HWSZ / 256, BB), 256, 0, stream>>>(x, off, w, bias, out);
    }
}

// Round 15
// 46.568 us; speedup vs baseline: 1.1948x; 1.0823x over previous
//
#include <hip/hip_runtime.h>

// Problem constants
#define BB 8
#define CC 64
#define OO 64
#define HH 128
#define WWI 128
#define HWSZ (HH * WWI)     // 16384
#define KK 9                // 3x3 taps
#define II (KK * CC)        // 576

// patch / window geometry (main kernel)
#define PXW 16              // patch width  (x)
#define PYH 16              // patch height (y)
#define WNX 24              // window cols = PXW + 8
#define WNY 24              // window rows = PYH + 8
#define WROWS (WNX * WNY)   // 576 window rows, each 64 ch * 2B = 128B -> 72KB

// LDS chunk-slot mix: fold row entropy (incl. y) into the 8-slot index.
// MUST be identical on staging-write and read (bijective per row).
#define MIXR(r) (((r) ^ ((r) >> 3)) & 7)

typedef __attribute__((ext_vector_type(8))) _Float16 half8;
typedef __attribute__((ext_vector_type(2))) _Float16 h2;
typedef __attribute__((ext_vector_type(4))) float f32x4;
typedef __attribute__((ext_vector_type(4))) unsigned int uint4v;

__device__ __forceinline__ int iclamp(int v, int lo, int hi) {
    return v < lo ? lo : (v > hi ? hi : v);
}
__device__ __forceinline__ unsigned short f2h(float f) {
    union { _Float16 h; unsigned short s; } v;
    v.h = (_Float16)f;
    return v.s;
}
__device__ __forceinline__ h2 u2h(unsigned u) {
    union { unsigned u; h2 h; } v;
    v.u = u;
    return v.h;
}

// ---------- merged prep: blocks [0,2048) transpose x -> xt (fp16 NHWC);
// blocks [2048, 2192) build the fragment-ordered W layout.
__global__ __launch_bounds__(256) void prep_all(const float* __restrict__ x,
                                                unsigned short* __restrict__ xt,
                                                const float* __restrict__ w,
                                                unsigned short* __restrict__ waf) {
    const int blk = blockIdx.x;
    const int t = threadIdx.x;
    if (blk < 2048) {
        __shared__ float tile[64][65];
        const int b = blk & 7;
        const int p0 = (blk >> 3) * 64;
        const int a = t >> 6;   // 0..3
        const int q = t & 63;   // 0..63
        const float* xb = x + (size_t)b * CC * HWSZ + p0;
#pragma unroll
        for (int r = 0; r < 16; ++r) {
            int c = r * 4 + a;
            tile[c][q] = xb[(size_t)c * HWSZ + q];   // coalesced read
        }
        __syncthreads();
        unsigned short* xo = xt + ((size_t)b * HWSZ + p0) * CC;
#pragma unroll
        for (int r = 0; r < 16; ++r) {
            int pl = r * 4 + a;
            xo[(size_t)pl * CC + q] = f2h(tile[q][pl]);  // coalesced write
        }
    } else {
        // waf[slab][lane][j], slab = (k*2+kc)*4 + m, value =
        //   W.flat[o = m*16+(lane&15)][i = k*64 + kc*32 + (lane>>4)*8 + j]
        int tid = (blk - 2048) * 256 + t;
        if (tid < 72 * 512) {
            int slab = tid >> 9;           // 0..71
            int r = tid & 511;
            int l = r >> 3, j = r & 7;
            int m = slab & 3;
            int kc = (slab >> 2) & 1;
            int k = slab >> 3;
            int o = m * 16 + (l & 15);
            int i = k * 64 + kc * 32 + (l >> 4) * 8 + j;
            waf[tid] = f2h(w[(size_t)o * II + i]);
        }
    }
}

// ---------- main: 16x16 patch per block, window in LDS, 8 waves.
// Depth-2 (tap,nt)-unit register pipeline (r11-validated) + improved LDS
// slot mix (MIXR) + setprio around the MFMA cluster.
__global__ __launch_bounds__(512, 2) void deform_mfma13(
        const unsigned short* __restrict__ xt,   // [B][H][W][C] fp16
        const float* __restrict__ off,           // [B][2K][H][W]
        const unsigned short* __restrict__ waf,  // frag-ordered W, fp16
        const float* __restrict__ bias,          // [O]
        float* __restrict__ out) {               // [B][O][H][W]
    extern __shared__ unsigned short win[];      // WROWS * 64 shorts = 72KB

    const int blk = blockIdx.x;
    const int b = blk & 7;                 // XCD-ownership: image b on XCD b
    const int pidx = blk >> 3;             // 0..63
    const int y0 = (pidx >> 3) * PYH;      // 8 y-patches
    const int x0 = (pidx & 7) * PXW;       // 8 x-patches
    const int xleft = x0 - 4, ytop = y0 - 4;

    const int t = threadIdx.x;
    const int wave = t >> 6;               // 0..7
    const int lane = t & 63;
    const int fm = lane & 15;              // px-in-tile (B col)
    const int hi = lane >> 4;              // 0..3 (k-chunk)
    const int c0s = hi * 8;                // short offset, kc=0 chunk
    const int c1s = 32 + hi * 8;           // short offset, kc=1 chunk

    const unsigned short* xtb = xt + (size_t)b * HWSZ * CC;
    const float* offpx = off + (size_t)b * 2 * KK * HWSZ
                             + (size_t)(y0 + wave * 2) * WWI + x0 + fm;

    // 3-slot offset ring (slot = tap%3); preload taps 0,1 before staging
    float ox[3][2], oy[3][2];
#pragma unroll
    for (int k = 0; k < 2; ++k) {
#pragma unroll
        for (int nt = 0; nt < 2; ++nt) {
            ox[k][nt] = offpx[(size_t)(2 * k + 0) * HWSZ + nt * WWI];
            oy[k][nt] = offpx[(size_t)(2 * k + 1) * HWSZ + nt * WWI];
        }
    }

    // ---- stage window: rows (cy,cx) in [ytop,ytop+23] x [xleft,xleft+23] ----
    {
        const int tch = t & 7;             // 16B chunk within a row
        const int rb = t >> 3;             // 0..63
#pragma unroll
        for (int sw = 0; sw < 9; ++sw) {
            const int r = sw * 64 + rb;    // window row 0..575
            const int wy = r / WNX, wx = r - wy * WNX;
            const int cy = ytop + wy, cx = xleft + wx;
            if (((unsigned)cy < (unsigned)HH) && ((unsigned)cx < (unsigned)WWI)) {
                const uint4v v = *(const uint4v*)(xtb + (size_t)(cy * WWI + cx) * CC + tch * 8);
                *(uint4v*)&win[r * CC + ((tch ^ MIXR(r)) << 3)] = v;  // swizzled
            }
        }
    }
    __syncthreads();

    f32x4 acc[2][4];
#pragma unroll
    for (int nt = 0; nt < 2; ++nt)
#pragma unroll
        for (int m = 0; m < 4; ++m) acc[nt][m] = (f32x4)(0.0f);

    // pipeline state (all indices compile-time constants after macro expansion)
    uint4v cb[2][8];       // corner vectors, buffer = unit&1 (== nt)
    float  cw[2][4];       // folded bilinear weights
    bool   inwf[2];        // in-window flag
    int    gidx[2][4];     // global fallback row indices
    half8  afb[2][8];      // A-fragments, buffer = tap&1

#define LDSRD(r, kc) (*(const uint4v*)&win[(r) * CC + ((((hi) + ((kc) << 2)) ^ MIXR(r)) << 3)])

    // ISSUE(u): coords + 8 ds_reads for unit u; on nt==0 also prefetch
    // offsets for tap k+2 (ring) and A-frags for tap k.
#define ISSUE(u) do {                                                           \
        if ((((u) & 1) == 0) && (((u) >> 1) + 2 < KK)) {                        \
            _Pragma("unroll")                                                   \
            for (int nt = 0; nt < 2; ++nt) {                                    \
                ox[(((u) >> 1) + 2) % 3][nt] =                                  \
                    offpx[(size_t)(2 * (((u) >> 1) + 2) + 0) * HWSZ + nt * WWI];\
                oy[(((u) >> 1) + 2) % 3][nt] =                                  \
                    offpx[(size_t)(2 * (((u) >> 1) + 2) + 1) * HWSZ + nt * WWI];\
            }                                                                   \
        }                                                                       \
        if (((u) & 1) == 0) {                                                   \
            const unsigned short* wk = waf + (size_t)((u) >> 1) * 8 * 512 + lane * 8; \
            _Pragma("unroll")                                                   \
            for (int q = 0; q < 8; ++q)                                         \
                afb[((u) >> 1) & 1][q] = *(const half8*)(wk + (size_t)q * 512); \
        }                                                                       \
        const float gx = ox[((u) >> 1) % 3][(u) & 1] + (float)(x0 + fm);        \
        const float gy = oy[((u) >> 1) % 3][(u) & 1] + (float)(y0 + wave * 2 + ((u) & 1)); \
        const float fxf = floorf(gx), fyf = floorf(gy);                         \
        const float fx = gx - fxf, fy = gy - fyf;                               \
        const int ux0 = (int)fxf - 1, ux1 = (int)fxf;                           \
        const int uy0 = (int)fyf - 1, uy1 = (int)fyf;                           \
        const float vx0 = ((unsigned)ux0 < (unsigned)WWI) ? 1.0f : 0.0f;        \
        const float vx1 = ((unsigned)ux1 < (unsigned)WWI) ? 1.0f : 0.0f;        \
        const float vy0 = ((unsigned)uy0 < (unsigned)HH) ? 1.0f : 0.0f;         \
        const float vy1 = ((unsigned)uy1 < (unsigned)HH) ? 1.0f : 0.0f;         \
        cw[(u) & 1][0] = (1.0f - fy) * (1.0f - fx) * vy0 * vx0;                 \
        cw[(u) & 1][1] = (1.0f - fy) * fx          * vy0 * vx1;                 \
        cw[(u) & 1][2] = fy          * (1.0f - fx) * vy1 * vx0;                 \
        cw[(u) & 1][3] = fy          * fx          * vy1 * vx1;                 \
        const int cx0 = iclamp(ux0, 0, WWI - 1), cx1 = iclamp(ux1, 0, WWI - 1); \
        const int cy0 = iclamp(uy0, 0, HH - 1),  cy1 = iclamp(uy1, 0, HH - 1);  \
        inwf[(u) & 1] = (cx0 >= xleft) & (cx1 <= xleft + WNX - 1)               \
                      & (cy0 >= ytop) & (cy1 <= ytop + WNY - 1);                \
        gidx[(u) & 1][0] = cy0 * WWI + cx0;  gidx[(u) & 1][1] = cy0 * WWI + cx1;\
        gidx[(u) & 1][2] = cy1 * WWI + cx0;  gidx[(u) & 1][3] = cy1 * WWI + cx1;\
        const int wx0 = iclamp(cx0 - xleft, 0, WNX - 1);                        \
        const int wx1 = iclamp(cx1 - xleft, 0, WNX - 1);                        \
        const int wy0 = iclamp(cy0 - ytop, 0, WNY - 1);                         \
        const int wy1 = iclamp(cy1 - ytop, 0, WNY - 1);                         \
        const int r00 = wy0 * WNX + wx0, r01 = wy0 * WNX + wx1;                 \
        const int r10 = wy1 * WNX + wx0, r11 = wy1 * WNX + wx1;                 \
        cb[(u) & 1][0] = LDSRD(r00, 0);  cb[(u) & 1][1] = LDSRD(r00, 1);        \
        cb[(u) & 1][2] = LDSRD(r01, 0);  cb[(u) & 1][3] = LDSRD(r01, 1);        \
        cb[(u) & 1][4] = LDSRD(r10, 0);  cb[(u) & 1][5] = LDSRD(r10, 1);        \
        cb[(u) & 1][6] = LDSRD(r11, 0);  cb[(u) & 1][7] = LDSRD(r11, 1);        \
    } while (0)

    // PROC(u): pin corner regs (loads complete HERE), rare global fallback,
    // packed-fp16 interp, 8 MFMA into acc[nt] (setprio-wrapped).
#define PROC(u) do {                                                            \
        asm volatile("" : "+v"(cb[(u) & 1][0]), "+v"(cb[(u) & 1][1]),           \
                          "+v"(cb[(u) & 1][2]), "+v"(cb[(u) & 1][3]),           \
                          "+v"(cb[(u) & 1][4]), "+v"(cb[(u) & 1][5]),           \
                          "+v"(cb[(u) & 1][6]), "+v"(cb[(u) & 1][7]));          \
        uint4v A0 = cb[(u) & 1][0], A1 = cb[(u) & 1][1];                        \
        uint4v B0 = cb[(u) & 1][2], B1 = cb[(u) & 1][3];                        \
        uint4v C0 = cb[(u) & 1][4], C1 = cb[(u) & 1][5];                        \
        uint4v D0 = cb[(u) & 1][6], D1 = cb[(u) & 1][7];                        \
        if (!inwf[(u) & 1]) {                                                   \
            const unsigned short* g00 = xtb + (size_t)gidx[(u) & 1][0] * CC;    \
            const unsigned short* g01 = xtb + (size_t)gidx[(u) & 1][1] * CC;    \
            const unsigned short* g10 = xtb + (size_t)gidx[(u) & 1][2] * CC;    \
            const unsigned short* g11 = xtb + (size_t)gidx[(u) & 1][3] * CC;    \
            A0 = *(const uint4v*)(g00 + c0s);  A1 = *(const uint4v*)(g00 + c1s);\
            B0 = *(const uint4v*)(g01 + c0s);  B1 = *(const uint4v*)(g01 + c1s);\
            C0 = *(const uint4v*)(g10 + c0s);  C1 = *(const uint4v*)(g10 + c1s);\
            D0 = *(const uint4v*)(g11 + c0s);  D1 = *(const uint4v*)(g11 + c1s);\
        }                                                                       \
        const _Float16 hw00 = (_Float16)cw[(u) & 1][0];                         \
        const _Float16 hw01 = (_Float16)cw[(u) & 1][1];                         \
        const _Float16 hw10 = (_Float16)cw[(u) & 1][2];                         \
        const _Float16 hw11 = (_Float16)cw[(u) & 1][3];                         \
        const h2 w00v = {hw00, hw00}, w01v = {hw01, hw01};                      \
        const h2 w10v = {hw10, hw10}, w11v = {hw11, hw11};                      \
        half8 bf0, bf1;                                                         \
        h2* rp0 = (h2*)&bf0;                                                    \
        h2* rp1 = (h2*)&bf1;                                                    \
        _Pragma("unroll")                                                       \
        for (int i = 0; i < 4; ++i) {                                           \
            h2 r0 = u2h(A0[i]) * w00v;                                          \
            r0 += u2h(B0[i]) * w01v;                                            \
            r0 += u2h(C0[i]) * w10v;                                            \
            r0 += u2h(D0[i]) * w11v;                                            \
            rp0[i] = r0;                                                        \
            h2 r1 = u2h(A1[i]) * w00v;                                          \
            r1 += u2h(B1[i]) * w01v;                                            \
            r1 += u2h(C1[i]) * w10v;                                            \
            r1 += u2h(D1[i]) * w11v;                                            \
            rp1[i] = r1;                                                        \
        }                                                                       \
        __builtin_amdgcn_s_setprio(1);                                          \
        _Pragma("unroll")                                                       \
        for (int m = 0; m < 4; ++m)                                             \
            acc[(u) & 1][m] = __builtin_amdgcn_mfma_f32_16x16x32_f16(           \
                afb[((u) >> 1) & 1][m], bf0, acc[(u) & 1][m], 0, 0, 0);         \
        _Pragma("unroll")                                                       \
        for (int m = 0; m < 4; ++m)                                             \
            acc[(u) & 1][m] = __builtin_amdgcn_mfma_f32_16x16x32_f16(           \
                afb[((u) >> 1) & 1][4 + m], bf1, acc[(u) & 1][m], 0, 0, 0);     \
        __builtin_amdgcn_s_setprio(0);                                          \
    } while (0)

    // Schedule (r11-validated): I0 I1 P0 I2 P1 ... I17 P16 P17
    ISSUE(0);  ISSUE(1);
    PROC(0);   ISSUE(2);
    PROC(1);   ISSUE(3);
    PROC(2);   ISSUE(4);
    PROC(3);   ISSUE(5);
    PROC(4);   ISSUE(6);
    PROC(5);   ISSUE(7);
    PROC(6);   ISSUE(8);
    PROC(7);   ISSUE(9);
    PROC(8);   ISSUE(10);
    PROC(9);   ISSUE(11);
    PROC(10);  ISSUE(12);
    PROC(11);  ISSUE(13);
    PROC(12);  ISSUE(14);
    PROC(13);  ISSUE(15);
    PROC(14);  ISSUE(16);
    PROC(15);  ISSUE(17);
    PROC(16);
    PROC(17);

#undef ISSUE
#undef PROC
#undef LDSRD

    // epilogue: D col = fm (px), D row = hi*4 + j within m-tile -> o = m*16+hi*4+j
#pragma unroll
    for (int nt = 0; nt < 2; ++nt) {
        float* outb = out + (size_t)b * OO * HWSZ
                          + (size_t)(y0 + wave * 2 + nt) * WWI + x0 + fm;
#pragma unroll
        for (int m = 0; m < 4; ++m) {
            const int ob = m * 16 + hi * 4;
            const float4 bs = *(const float4*)(bias + ob);
#pragma unroll
            for (int j = 0; j < 4; ++j) {
                outb[(size_t)(ob + j) * HWSZ] = acc[nt][m][j] + ((const float*)&bs)[j];
            }
        }
    }
}

// ---------- fallback (round-1 fp32 path, used only if ws too small) ----------
__global__ __launch_bounds__(256) void deform_conv_fallback(
        const float* __restrict__ x, const float* __restrict__ off,
        const float* __restrict__ wmat, const float* __restrict__ bias,
        float* __restrict__ out) {
    const int b = blockIdx.y;
    const int p = blockIdx.x * 256 + threadIdx.x;
    const int wo = p & (WWI - 1);
    const int ho = p >> 7;
    const float* xb = x + (size_t)b * CC * HWSZ;
    const float* offb = off + (size_t)b * 2 * KK * HWSZ + p;
    float acc[OO];
#pragma unroll
    for (int o = 0; o < OO; ++o) acc[o] = 0.0f;
#pragma unroll 1
    for (int k = 0; k < KK; ++k) {
        const float gx = offb[(size_t)(2 * k + 0) * HWSZ] + (float)wo;
        const float gy = offb[(size_t)(2 * k + 1) * HWSZ] + (float)ho;
        const float fxf = floorf(gx), fyf = floorf(gy);
        const float fx = gx - fxf, fy = gy - fyf;
        const int ux0 = (int)fxf - 1, ux1 = (int)fxf;
        const int uy0 = (int)fyf - 1, uy1 = (int)fyf;
        const float vx0 = ((unsigned)ux0 < (unsigned)WWI) ? 1.0f : 0.0f;
        const float vx1 = ((unsigned)ux1 < (unsigned)WWI) ? 1.0f : 0.0f;
        const float vy0 = ((unsigned)uy0 < (unsigned)HH) ? 1.0f : 0.0f;
        const float vy1 = ((unsigned)uy1 < (unsigned)HH) ? 1.0f : 0.0f;
        const float w00 = (1.0f - fy) * (1.0f - fx) * vy0 * vx0;
        const float w01 = (1.0f - fy) * fx * vy0 * vx1;
        const float w10 = fy * (1.0f - fx) * vy1 * vx0;
        const float w11 = fy * fx * vy1 * vx1;
        const int cx0 = iclamp(ux0, 0, WWI - 1), cx1 = iclamp(ux1, 0, WWI - 1);
        const int cy0 = iclamp(uy0, 0, HH - 1), cy1 = iclamp(uy1, 0, HH - 1);
        const int i00 = cy0 * WWI + cx0, i01 = cy0 * WWI + cx1;
        const int i10 = cy1 * WWI + cx0, i11 = cy1 * WWI + cx1;
#pragma unroll 4
        for (int c = 0; c < CC; ++c) {
            const float* xc = xb + (size_t)c * HWSZ;
            const float v = w00 * xc[i00] + w01 * xc[i01] + w10 * xc[i10] + w11 * xc[i11];
            const float* wrow = wmat + (size_t)(k * CC + c);
#pragma unroll
            for (int o = 0; o < OO; ++o) acc[o] = fmaf(wrow[(size_t)o * II], v, acc[o]);
        }
    }
    float* outb = out + (size_t)b * OO * HWSZ + p;
#pragma unroll
    for (int o = 0; o < OO; ++o) outb[(size_t)o * HWSZ] = acc[o] + bias[o];
}

extern "C" void kernel_launch(void* const* d_in, const int* in_sizes, int n_in,
                              void* d_out, int out_size, void* d_ws, size_t ws_size,
                              hipStream_t stream) {
    const float* x    = (const float*)d_in[0];
    const float* off  = (const float*)d_in[1];
    const float* w    = (const float*)d_in[2];
    const float* bias = (const float*)d_in[3];
    float* out = (float*)d_out;

    const size_t xt_bytes  = (size_t)BB * HWSZ * CC * sizeof(unsigned short); // 16.78 MB
    const size_t waf_bytes = (size_t)72 * 512 * sizeof(unsigned short);       // 73728 B

    if (ws_size >= xt_bytes + waf_bytes) {
        unsigned short* xtp = (unsigned short*)d_ws;
        unsigned short* wfp = (unsigned short*)((char*)d_ws + xt_bytes);
        prep_all<<<dim3(2048 + 144), 256, 0, stream>>>(x, xtp, w, wfp);
        // 8 images x (8 y-patches * 8 x-patches) = 512 blocks, 72KB dyn LDS
        deform_mfma13<<<dim3(BB * (HH / PYH) * (WWI / PXW)), dim3(512),
                        WROWS * CC * sizeof(unsigned short), stream>>>(
            xtp, off, wfp, bias, out);
    } else {
        deform_conv_fallback<<<dim3(HWSZ / 256, BB), 256, 0, stream>>>(x, off, w, bias, out);
    }
}